// Round 1
// baseline (244.892 us; speedup 1.0000x reference)
//
#include <hip/hip_runtime.h>

// Problem constants (match reference file)
constexpr int B = 32768;
constexpr int D = 1024;
constexpr int S = 64;
constexpr int O = 4;

// One wave (64 lanes) per batch row.
// Lane l handles d in {k*256 + 4l + j : k=0..3, j=0..3} via float4 loads:
//   - x loads: 64 lanes * 16B = 1 KiB coalesced per instruction
//   - W loads: W[sid, d, 0:4] is a contiguous float4 (row-major [S, D, O], O=4)
// fp32 accumulate 4 partial outputs per lane, 6-step shfl_xor butterfly,
// lane 0 adds bias and writes float4.
__global__ __launch_bounds__(256) void tl_heads_kernel(
    const float* __restrict__ x,      // [B, D]
    const int*   __restrict__ sid,    // [B]
    const float* __restrict__ W,      // [S, D, O]
    const float* __restrict__ bias,   // [S, O]
    float*       __restrict__ out)    // [B, O]
{
    const int gtid = blockIdx.x * blockDim.x + threadIdx.x;
    const int row  = gtid >> 6;        // wave index == batch row
    const int lane = threadIdx.x & 63;
    if (row >= B) return;

    const int s = sid[row];
    const float* __restrict__ xr = x + (size_t)row * D;
    const float* __restrict__ Wr = W + (size_t)s * (D * O);

    float a0 = 0.f, a1 = 0.f, a2 = 0.f, a3 = 0.f;

    #pragma unroll
    for (int k = 0; k < 4; ++k) {
        const int d0 = k * 256 + lane * 4;
        const float4 xv = *(const float4*)(xr + d0);
        const float4 w0 = *(const float4*)(Wr + (size_t)(d0 + 0) * O);
        const float4 w1 = *(const float4*)(Wr + (size_t)(d0 + 1) * O);
        const float4 w2 = *(const float4*)(Wr + (size_t)(d0 + 2) * O);
        const float4 w3 = *(const float4*)(Wr + (size_t)(d0 + 3) * O);
        a0 += xv.x * w0.x + xv.y * w1.x + xv.z * w2.x + xv.w * w3.x;
        a1 += xv.x * w0.y + xv.y * w1.y + xv.z * w2.y + xv.w * w3.y;
        a2 += xv.x * w0.z + xv.y * w1.z + xv.z * w2.z + xv.w * w3.z;
        a3 += xv.x * w0.w + xv.y * w1.w + xv.z * w2.w + xv.w * w3.w;
    }

    // Wave-64 butterfly reduction
    #pragma unroll
    for (int off = 32; off >= 1; off >>= 1) {
        a0 += __shfl_xor(a0, off, 64);
        a1 += __shfl_xor(a1, off, 64);
        a2 += __shfl_xor(a2, off, 64);
        a3 += __shfl_xor(a3, off, 64);
    }

    if (lane == 0) {
        const float4 bv = *(const float4*)(bias + s * O);
        float4 o4;
        o4.x = a0 + bv.x;
        o4.y = a1 + bv.y;
        o4.z = a2 + bv.z;
        o4.w = a3 + bv.w;
        *(float4*)(out + (size_t)row * O) = o4;
    }
}

extern "C" void kernel_launch(void* const* d_in, const int* in_sizes, int n_in,
                              void* d_out, int out_size, void* d_ws, size_t ws_size,
                              hipStream_t stream) {
    const float* x    = (const float*)d_in[0];   // [B, D]
    const int*   sid  = (const int*)d_in[1];     // [B]
    const float* W    = (const float*)d_in[2];   // [S, D, O]
    const float* bias = (const float*)d_in[3];   // [S, O]
    float* out = (float*)d_out;                  // [B, O]

    // 1 wave per row; 4 waves per 256-thread block
    const int blocks = B / 4;  // 8192
    tl_heads_kernel<<<blocks, 256, 0, stream>>>(x, sid, W, bias, out);
}

// Round 2
// 205.056 us; speedup vs baseline: 1.1943x; 1.1943x over previous
//
#include <hip/hip_runtime.h>

// Problem constants (match reference file)
constexpr int B = 32768;
constexpr int D = 1024;
constexpr int S = 64;
constexpr int O = 4;

// One wave (64 lanes) per batch row, lane l owns d = k*64 + l.
//   - W load: W[s, d, 0:4] float4, lanes 16 B apart -> fully coalesced 1 KiB/instr
//   - x load: scalar float, lanes 4 B apart -> coalesced 256 B/instr
// W is only 1 MiB total -> L2-resident; x (128 MiB) streams from HBM once.
__global__ __launch_bounds__(256) void tl_heads_kernel(
    const float* __restrict__ x,      // [B, D]
    const int*   __restrict__ sid,    // [B]
    const float* __restrict__ W,      // [S, D, O]
    const float* __restrict__ bias,   // [S, O]
    float*       __restrict__ out)    // [B, O]
{
    const int gtid = blockIdx.x * blockDim.x + threadIdx.x;
    const int row  = gtid >> 6;        // wave index == batch row
    const int lane = threadIdx.x & 63;
    if (row >= B) return;

    const int s = sid[row];
    const float* __restrict__ xr = x + (size_t)row * D;
    const float* __restrict__ Wr = W + (size_t)s * (D * O);

    float a0 = 0.f, a1 = 0.f, a2 = 0.f, a3 = 0.f;

    #pragma unroll
    for (int k = 0; k < 16; ++k) {
        const int d = k * 64 + lane;
        const float  xv = xr[d];
        const float4 wv = *(const float4*)(Wr + (size_t)d * O);
        a0 += xv * wv.x;
        a1 += xv * wv.y;
        a2 += xv * wv.z;
        a3 += xv * wv.w;
    }

    // Wave-64 butterfly reduction
    #pragma unroll
    for (int off = 32; off >= 1; off >>= 1) {
        a0 += __shfl_xor(a0, off, 64);
        a1 += __shfl_xor(a1, off, 64);
        a2 += __shfl_xor(a2, off, 64);
        a3 += __shfl_xor(a3, off, 64);
    }

    if (lane == 0) {
        const float4 bv = *(const float4*)(bias + s * O);
        float4 o4;
        o4.x = a0 + bv.x;
        o4.y = a1 + bv.y;
        o4.z = a2 + bv.z;
        o4.w = a3 + bv.w;
        *(float4*)(out + (size_t)row * O) = o4;
    }
}

extern "C" void kernel_launch(void* const* d_in, const int* in_sizes, int n_in,
                              void* d_out, int out_size, void* d_ws, size_t ws_size,
                              hipStream_t stream) {
    const float* x    = (const float*)d_in[0];   // [B, D]
    const int*   sid  = (const int*)d_in[1];     // [B]
    const float* W    = (const float*)d_in[2];   // [S, D, O]
    const float* bias = (const float*)d_in[3];   // [S, O]
    float* out = (float*)d_out;                  // [B, O]

    // 1 wave per row; 4 waves per 256-thread block
    const int blocks = B / 4;  // 8192
    tl_heads_kernel<<<blocks, 256, 0, stream>>>(x, sid, W, bias, out);
}